// Round 16
// baseline (601.253 us; speedup 1.0000x reference)
//
#include <hip/hip_runtime.h>
#include <math.h>

#define T_STEPS 120
#define BATCH   1024
#define NBK     64        // batch groups of 16

typedef __attribute__((ext_vector_type(8))) short bf16x8;
typedef __attribute__((ext_vector_type(4))) float f32x4;
typedef __attribute__((ext_vector_type(4))) unsigned short us4;
typedef unsigned short u16;

// round-to-nearest-even bf16
__device__ __forceinline__ short bf16rne(float f) {
    union { float f; unsigned u; } a; a.f = f;
    unsigned r = a.u + 0x7FFFu + ((a.u >> 16) & 1);
    return (short)(r >> 16);
}

__device__ __forceinline__ float fast_sigmoid(float x) {
    float e = __expf(-x);
    return __builtin_amdgcn_rcpf(1.f + e);
}

// LDS-visibility-only barrier: does NOT drain vmcnt, so global prefetch
// loads and h stores stay in flight across the step boundary.
__device__ __forceinline__ void block_sync_lds() {
    asm volatile("s_waitcnt lgkmcnt(0)" ::: "memory");
    __builtin_amdgcn_sched_barrier(0);
    __builtin_amdgcn_s_barrier();
    __builtin_amdgcn_sched_barrier(0);
}

// ---------------------------------------------------------------------------
// x (B,T,132) fp32 -> frag-major bf16 XF[t][bk 64][kt 5][lane 64][e 8],
// b = bk*16 + (lane&15), k = kt*32 + (lane>>4)*8 + e  (0 for k>=132).
// ---------------------------------------------------------------------------
__global__ __launch_bounds__(256)
void xconv(const float* __restrict__ x, u16* __restrict__ xf)
{
    int tid  = blockIdx.x * 256 + threadIdx.x;
    int lane = tid & 63;
    int rest = tid >> 6;
    int kt   = rest % 5;
    int tbk  = rest / 5;
    int bk   = tbk & 63;
    int t    = tbk >> 6;
    int ln   = lane & 15, lq = lane >> 4;
    int b    = bk * 16 + ln;
    int k0   = kt * 32 + lq * 8;
    const float* src = &x[((size_t)b * T_STEPS + t) * 132];
    u16 out[8];
#pragma unroll
    for (int e = 0; e < 8; ++e) {
        int k = k0 + e;
        out[e] = (u16)bf16rne((k < 132) ? src[k] : 0.f);
    }
    us4 o0, o1;
    o0.x = out[0]; o0.y = out[1]; o0.z = out[2]; o0.w = out[3];
    o1.x = out[4]; o1.y = out[5]; o1.z = out[6]; o1.w = out[7];
    *reinterpret_cast<us4*>(&xf[(size_t)tid * 8])     = o0;
    *reinterpret_cast<us4*>(&xf[(size_t)tid * 8 + 4]) = o1;
}

// ---------------------------------------------------------------------------
// Phased fused LSTM layer: 256 threads = 4 waves, 1 wave/SIMD, 256-VGPR
// budget ((256,1) + waves_per_eu(1,1)). Each wave runs TWO independent
// phases per step (ILP fills latencies):
//   UNITPH=false (U=64): phases = batch halves; NBT=32, grid 32.
//   UNITPH=true  (U=128): phases = unit groups (wid, wid+4); NBT=16, grid 64;
//                 h-frags shared between phases.
// Recurrent h is single RNE-bf16 (one LDS plane, double-buffered).
// Weights: U (+W unless WXLDS) register-resident single bf16; L2's W in LDS.
// One lgkm-only barrier per step.
// ---------------------------------------------------------------------------
template<int U, int NBT, int KTXI, int KTXO, bool UNITPH, bool WXLDS, bool LAST_ONLY>
__global__ __launch_bounds__(256, 1)
__attribute__((amdgpu_waves_per_eu(1, 1)))
void lstm_ph(const u16* __restrict__ xf,
             const float* __restrict__ W, int KIN,
             const float* __restrict__ Uw, const float* __restrict__ bias,
             u16* __restrict__ hf, float* __restrict__ hlast)
{
    constexpr int NZ  = 4 * U;
    constexpr int KTH = U / 32;
    constexpr int HPLANE = NBT * U;           // u16 per buffer (single plane)
    constexpr int PHU = UNITPH ? 2 : 1;       // distinct unit-phases
    constexpr int PHB = UNITPH ? 1 : 2;       // distinct batch-phases
    constexpr size_t XSTRIDE = (size_t)NBK * KTXI * 512;
    constexpr size_t OSTRIDE = (size_t)NBK * KTXO * 512;

    __shared__ u16 hsh[2 * HPLANE];
    __shared__ u16 Wl[WXLDS ? KTXI * 32 * NZ : 64];

    const int tid  = threadIdx.x;
    const int lane = tid & 63;
    const int wid  = tid >> 6;
    const int ln   = lane & 15;
    const int lq   = lane >> 4;
    const int b0   = blockIdx.x * NBT;

    int unitp[2], bbp[2];
#pragma unroll
    for (int pp = 0; pp < 2; ++pp) {
        unitp[pp] = (UNITPH ? (wid + 4 * pp) : wid) * 16 + ln;
        bbp[pp]   = UNITPH ? 0 : pp * 16;
    }

    // ---- stage W into LDS if requested (L2) ----
    if constexpr (WXLDS) {
        for (int idx = tid; idx < KTXI * 32 * NZ; idx += 256) {
            int k = idx / NZ, n = idx % NZ;
            float f = (k < KIN) ? W[(size_t)k * NZ + n] : 0.f;
            Wl[((k >> 3) * NZ + n) * 8 + (k & 7)] = (u16)bf16rne(f);
        }
    }

    // ---- U weights into registers (per unit-phase) ----
    bf16x8 bwu[PHU][4][KTH];
#pragma unroll
    for (int up = 0; up < PHU; ++up)
#pragma unroll
        for (int p4 = 0; p4 < 4; ++p4)
#pragma unroll
            for (int kt = 0; kt < KTH; ++kt)
#pragma unroll
                for (int e = 0; e < 8; ++e) {
                    int k = kt * 32 + lq * 8 + e;
                    bwu[up][p4][kt][e] = bf16rne(Uw[(size_t)k * NZ + p4 * U + unitp[up]]);
                }
    float breg[PHU][4];
#pragma unroll
    for (int up = 0; up < PHU; ++up)
#pragma unroll
        for (int p4 = 0; p4 < 4; ++p4) breg[up][p4] = bias[p4 * U + unitp[up]];

    // ---- W weights into registers (batch-phased layers; shared by phases) ----
    bf16x8 wxw[4][KTXI];
    if constexpr (!WXLDS) {
#pragma unroll
        for (int p4 = 0; p4 < 4; ++p4)
#pragma unroll
            for (int kt = 0; kt < KTXI; ++kt)
#pragma unroll
                for (int e = 0; e < 8; ++e) {
                    int k = kt * 32 + lq * 8 + e;
                    wxw[p4][kt][e] = (k < KIN) ? bf16rne(W[(size_t)k * NZ + p4 * U + unitp[0]])
                                               : (short)0;
                }
    }

    // ---- Wl read bases (unit-phased) ----
    const u16* wbp[2];
#pragma unroll
    for (int pp = 0; pp < 2; ++pp)
        wbp[pp] = Wl + ((size_t)lq * NZ + unitp[pp]) * 8;

    // ---- h state: write pointers, zero buf0, c regs ----
    u16* hwp[2][2];
    float creg[2][4];
#pragma unroll
    for (int pp = 0; pp < 2; ++pp) {
        int base = ((unitp[pp] >> 3) * NBT + bbp[pp] + lq * 4) * 8 + (unitp[pp] & 7);
        hwp[pp][0] = hsh + base;
        hwp[pp][1] = hsh + HPLANE + base;
#pragma unroll
        for (int r = 0; r < 4; ++r) {
            creg[pp][r] = 0.f;
            hwp[pp][0][r * 8] = 0;
        }
    }

    // ---- h read pointers (per batch-phase; shared across unit-phases) ----
    const u16* hrd[2][PHB][KTH];
#pragma unroll
    for (int bf = 0; bf < 2; ++bf)
#pragma unroll
        for (int pb = 0; pb < PHB; ++pb)
#pragma unroll
            for (int kt = 0; kt < KTH; ++kt)
                hrd[bf][pb][kt] = hsh + bf * HPLANE + ((kt * 4 + lq) * NBT + bbp[pb] + ln) * 8;

    // ---- x frag pointers + first prefetch ----
    const u16* pxf[PHB];
    bf16x8 xfh[PHB][KTXI];
#pragma unroll
    for (int pb = 0; pb < PHB; ++pb) {
        int bkw = (b0 + bbp[pb]) >> 4;
        pxf[pb] = xf + (size_t)bkw * KTXI * 512 + lane * 8;
#pragma unroll
        for (int kt = 0; kt < KTXI; ++kt)
            xfh[pb][kt] = *reinterpret_cast<const bf16x8*>(pxf[pb] + kt * 512);
    }

    // ---- output pointers (frag-major for next layer) ----
    u16* hfo[2] = {nullptr, nullptr};
    if constexpr (!LAST_ONLY) {
#pragma unroll
        for (int pp = 0; pp < 2; ++pp) {
            int kto = unitp[pp] >> 5;
            int lqp = (unitp[pp] >> 3) & 3;
            int ep  = unitp[pp] & 7;
            int bkw = (b0 + bbp[pp]) >> 4;
            hfo[pp] = hf + (((size_t)bkw * KTXO + kto) * 64 + lqp * 16 + lq * 4) * 8 + ep;
        }
    }

    block_sync_lds();

#define PSTEP(CUR, OTH, tc)                                                     \
    {                                                                           \
        bf16x8 ah[PHB][KTH];                                                    \
        _Pragma("unroll")                                                       \
        for (int pb = 0; pb < PHB; ++pb)                                        \
        _Pragma("unroll")                                                       \
        for (int kt = 0; kt < KTH; ++kt)                                        \
            ah[pb][kt] = *reinterpret_cast<const bf16x8*>(hrd[CUR][pb][kt]);    \
        f32x4 acc[2][4] = {};                                                   \
        /* x-part first: frags already in registers */                          \
        _Pragma("unroll")                                                       \
        for (int pp = 0; pp < 2; ++pp) {                                        \
            constexpr int _dummy = 0; (void)_dummy;                             \
            _Pragma("unroll")                                                   \
            for (int kt = 0; kt < KTXI; ++kt)                                   \
            _Pragma("unroll")                                                   \
            for (int p4 = 0; p4 < 4; ++p4) {                                    \
                bf16x8 wf;                                                      \
                if constexpr (WXLDS)                                            \
                    wf = *reinterpret_cast<const bf16x8*>(                      \
                        wbp[pp] + ((size_t)kt * 4 * NZ + p4 * U) * 8);          \
                else                                                            \
                    wf = wxw[p4][kt];                                           \
                acc[pp][p4] = __builtin_amdgcn_mfma_f32_16x16x32_bf16(          \
                    xfh[UNITPH ? 0 : pp][kt], wf, acc[pp][p4], 0, 0, 0);        \
            }                                                                   \
        }                                                                       \
        /* h-part */                                                            \
        _Pragma("unroll")                                                       \
        for (int pp = 0; pp < 2; ++pp)                                          \
        _Pragma("unroll")                                                       \
        for (int kt = 0; kt < KTH; ++kt)                                        \
        _Pragma("unroll")                                                       \
        for (int p4 = 0; p4 < 4; ++p4)                                          \
            acc[pp][p4] = __builtin_amdgcn_mfma_f32_16x16x32_bf16(              \
                ah[UNITPH ? 0 : pp][kt], bwu[UNITPH ? pp : 0][p4][kt],          \
                acc[pp][p4], 0, 0, 0);                                          \
        /* prefetch next x */                                                   \
        if ((tc) + 1 < T_STEPS) {                                               \
            _Pragma("unroll")                                                   \
            for (int pb = 0; pb < PHB; ++pb) {                                  \
                pxf[pb] += XSTRIDE;                                             \
                _Pragma("unroll")                                               \
                for (int kt = 0; kt < KTXI; ++kt)                               \
                    xfh[pb][kt] = *reinterpret_cast<const bf16x8*>(pxf[pb] + kt * 512); \
            }                                                                   \
        }                                                                       \
        /* gates + state + h writes */                                          \
        _Pragma("unroll")                                                       \
        for (int pp = 0; pp < 2; ++pp) {                                        \
            const int up = UNITPH ? pp : 0;                                     \
            _Pragma("unroll")                                                   \
            for (int r = 0; r < 4; ++r) {                                       \
                float si = fast_sigmoid(acc[pp][0][r] + breg[up][0]);           \
                float sf = fast_sigmoid(acc[pp][1][r] + breg[up][1]);           \
                float gg = fmaxf(acc[pp][2][r] + breg[up][2], 0.f);             \
                float so = fast_sigmoid(acc[pp][3][r] + breg[up][3]);           \
                float c  = sf * creg[pp][r] + si * gg;                          \
                creg[pp][r] = c;                                                \
                float h = so * fmaxf(c, 0.f);                                   \
                u16 hb = (u16)bf16rne(h);                                       \
                hwp[pp][OTH][r * 8] = hb;                                       \
                if constexpr (!LAST_ONLY) {                                     \
                    hfo[pp][(size_t)(tc) * OSTRIDE + r * 8] = hb;               \
                } else {                                                        \
                    if ((tc) == T_STEPS - 1)                                    \
                        hlast[(size_t)(b0 + bbp[pp] + lq * 4 + r) * U + unitp[pp]] = h; \
                }                                                               \
            }                                                                   \
        }                                                                       \
        block_sync_lds();                                                       \
    }

    for (int t = 0; t < T_STEPS; t += 2) {
        PSTEP(0, 1, t)
        PSTEP(1, 0, t + 1)
    }
#undef PSTEP
}

// Dense head: one wave per batch row. 64 ->relu-> 64 ->relu-> 32 -> 101 -> softmax
__global__ __launch_bounds__(256)
void dense_head(const float* __restrict__ h3,    // (B,64)
                const float* __restrict__ Wd1, const float* __restrict__ bd1,
                const float* __restrict__ Wd2, const float* __restrict__ bd2,
                const float* __restrict__ Wd3, const float* __restrict__ bd3,
                float* __restrict__ out)         // (B,101)
{
    __shared__ float s1[4][64];
    __shared__ float s2[4][32];
    const int w    = threadIdx.x >> 6;
    const int lane = threadIdx.x & 63;
    const int row  = blockIdx.x * 4 + w;

    float hval = h3[(size_t)row * 64 + lane];
    float a = bd1[lane];
#pragma unroll
    for (int k = 0; k < 64; ++k) {
        float hk = __shfl(hval, k, 64);
        a = fmaf(hk, Wd1[k * 64 + lane], a);
    }
    s1[w][lane] = fmaxf(a, 0.f);
    __syncthreads();

    if (lane < 32) {
        float a2 = bd2[lane];
#pragma unroll
        for (int k = 0; k < 64; ++k) a2 = fmaf(s1[w][k], Wd2[k * 32 + lane], a2);
        s2[w][lane] = fmaxf(a2, 0.f);
    }
    __syncthreads();

    float a0 = bd3[lane];
#pragma unroll
    for (int k = 0; k < 32; ++k) a0 = fmaf(s2[w][k], Wd3[k * 101 + lane], a0);
    float a1 = -INFINITY;
    if (lane < 37) {
        a1 = bd3[64 + lane];
#pragma unroll
        for (int k = 0; k < 32; ++k) a1 = fmaf(s2[w][k], Wd3[k * 101 + 64 + lane], a1);
    }

    float m = fmaxf(a0, a1);
#pragma unroll
    for (int off = 32; off > 0; off >>= 1) m = fmaxf(m, __shfl_xor(m, off, 64));
    float e0 = expf(a0 - m);
    float e1 = (lane < 37) ? expf(a1 - m) : 0.f;
    float s = e0 + e1;
#pragma unroll
    for (int off = 32; off > 0; off >>= 1) s += __shfl_xor(s, off, 64);

    out[(size_t)row * 101 + lane] = e0 / s;
    if (lane < 37) out[(size_t)row * 101 + 64 + lane] = e1 / s;
}

extern "C" void kernel_launch(void* const* d_in, const int* in_sizes, int n_in,
                              void* d_out, int out_size, void* d_ws, size_t ws_size,
                              hipStream_t stream) {
    const float* x   = (const float*)d_in[0];
    const float* W1  = (const float*)d_in[1];
    const float* U1  = (const float*)d_in[2];
    const float* b1  = (const float*)d_in[3];
    const float* W2  = (const float*)d_in[4];
    const float* U2  = (const float*)d_in[5];
    const float* b2  = (const float*)d_in[6];
    const float* W3  = (const float*)d_in[7];
    const float* U3  = (const float*)d_in[8];
    const float* b3  = (const float*)d_in[9];
    const float* Wd1 = (const float*)d_in[10];
    const float* bd1 = (const float*)d_in[11];
    const float* Wd2 = (const float*)d_in[12];
    const float* bd2 = (const float*)d_in[13];
    const float* Wd3 = (const float*)d_in[14];
    const float* bd3 = (const float*)d_in[15];

    // workspace (u16 units), frag-major activation buffers
    u16* ws16 = (u16*)d_ws;
    u16* xfb  = ws16;                         // 120*64*5*512 = 19,660,800
    u16* h1f  = ws16 + 19660800;              // 120*64*2*512 = 7,864,320
    u16* h2f  = h1f + 7864320;                // 120*64*4*512 = 15,728,640
    float* h3 = (float*)(ws16 + 43253760);    // 1024*64 fp32

    // 1) x -> frag-major bf16 (zero-padded to 160 k)
    xconv<<<(T_STEPS * NBK * 5 * 64) / 256, 256, 0, stream>>>(x, xfb);
    // 2) layer 1: U=64, batch-phased, W1+U1 in regs, grid 32
    lstm_ph<64, 32, 5, 2, false, false, false><<<32, 256, 0, stream>>>(
        xfb, W1, 132, U1, b1, h1f, nullptr);
    // 3) layer 2: U=128, unit-phased, W2 in LDS, U2 in regs, grid 64
    lstm_ph<128, 16, 2, 4, true, true, false><<<64, 256, 0, stream>>>(
        h1f, W2, 64, U2, b2, h2f, nullptr);
    // 4) layer 3: U=64, batch-phased, W3+U3 in regs, grid 32, last h only
    lstm_ph<64, 32, 4, 1, false, false, true><<<32, 256, 0, stream>>>(
        h2f, W3, 128, U3, b3, nullptr, h3);
    // 5) dense head + softmax
    dense_head<<<BATCH / 4, 256, 0, stream>>>(h3, Wd1, bd1, Wd2, bd2, Wd3, bd3,
                                              (float*)d_out);
}

// Round 17
// 538.704 us; speedup vs baseline: 1.1161x; 1.1161x over previous
//
#include <hip/hip_runtime.h>
#include <math.h>

#define T_STEPS 120
#define BATCH   1024

typedef __attribute__((ext_vector_type(8))) short bf16x8;
typedef __attribute__((ext_vector_type(4))) float f32x4;
typedef __attribute__((ext_vector_type(4))) unsigned short us4;
typedef unsigned short u16;

// GEMM LDS slot swizzle (proven R5)
__device__ __forceinline__ int gsw(int r) { return (r & 7) ^ ((r >> 3) & 1); }

// round-to-nearest-even bf16
__device__ __forceinline__ u16 bf16rne(float f) {
    union { float f; unsigned u; } a; a.f = f;
    unsigned r = a.u + 0x7FFFu + ((a.u >> 16) & 1);
    return (u16)(r >> 16);
}

__device__ __forceinline__ float bf2f(u16 v) {
    union { unsigned u; float f; } a; a.u = ((unsigned)v) << 16;
    return a.f;
}

__device__ __forceinline__ float fast_sigmoid(float x) {
    float e = __expf(-x);
    return __builtin_amdgcn_rcpf(1.f + e);
}

// LDS-visibility-only barrier (keeps global loads/stores in flight)
__device__ __forceinline__ void block_sync_lds() {
    asm volatile("s_waitcnt lgkmcnt(0)" ::: "memory");
    __builtin_amdgcn_sched_barrier(0);
    __builtin_amdgcn_s_barrier();
    __builtin_amdgcn_sched_barrier(0);
}

// ---------------------------------------------------------------------------
// Single-term bf16 MFMA GEMM (R5 skeleton, proven layout/swizzle):
//   xz[m,n] = sum_k A[m,k] * W[k,n],  m = b*120 + t  (M = 122880).
// A: fp32 (AF32) or bf16-u16 rows of length K. W: fp32 (K,N).
// Output: frag-major bf16 XZF[t][bk][p4*4+ug][lane][r] for the rec kernel:
//   b = bk*16 + (lane>>4)*4 + r, n = (p4*4+ug)*16 + (lane&15).
// BM=128, BN=64, BK=64, 256 threads = 4 waves, wave tile 64x32.
// ---------------------------------------------------------------------------
template<bool AF32>
__global__ __launch_bounds__(256, 2)
void gemm_xz(const void* __restrict__ Av, const float* __restrict__ Bw,
             u16* __restrict__ XZF, int N, int K)
{
    constexpr int BM = 128, BN = 64, BK = 64;
    __shared__ u16 Ah[BM * BK];
    __shared__ u16 Bh[BN * BK];

    const float* Af = (const float*)Av;
    const u16*   Ab = (const u16*)Av;

    const int tid  = threadIdx.x;
    const int lane = tid & 63;
    const int wv   = tid >> 6;
    const int wm   = wv & 1;
    const int wn   = wv >> 1;
    const int m0   = blockIdx.x * BM;
    const int n0   = blockIdx.y * BN;

    f32x4 acc[4][2] = {};

    const int ktiles = (K + BK - 1) / BK;
    for (int kt = 0; kt < ktiles; ++kt) {
        const int kb = kt * BK;
        __syncthreads();

        // stage A tile: row = rd*16 + (tid>>4), 4 k-elems per thread (f4)
        {
            const int f4   = tid & 15;
            const int sub  = (f4 & 1) * 4;
            const int k8   = f4 >> 1;
            const int kidx = kb + f4 * 4;
            const bool kok = (kidx < K);          // K % 4 == 0 always
            for (int rd = 0; rd < 8; ++rd) {
                int m  = rd * 16 + (tid >> 4);
                int gm = m0 + m;
                us4 hh;
                if (kok) {
                    if constexpr (AF32) {
                        float4 v = *reinterpret_cast<const float4*>(
                            &Af[(size_t)gm * K + kidx]);
                        hh.x = bf16rne(v.x); hh.y = bf16rne(v.y);
                        hh.z = bf16rne(v.z); hh.w = bf16rne(v.w);
                    } else {
                        hh = *reinterpret_cast<const us4*>(
                            &Ab[(size_t)gm * K + kidx]);
                    }
                } else {
                    hh.x = 0; hh.y = 0; hh.z = 0; hh.w = 0;
                }
                int off = m * 64 + ((k8 ^ gsw(m & 15)) * 8) + sub;
                *reinterpret_cast<us4*>(&Ah[off]) = hh;
            }
        }
        // stage B tile transposed: 512 units of 8 shorts; 2 units/thread
        {
#pragma unroll
            for (int i = 0; i < 2; ++i) {
                int u  = tid + i * 256;
                int n  = u & 63;
                int k8 = u >> 6;
                u16 th[8];
#pragma unroll
                for (int e = 0; e < 8; ++e) {
                    int k = kb + k8 * 8 + e;
                    th[e] = (k < K) ? bf16rne(Bw[(size_t)k * N + n0 + n]) : (u16)0;
                }
                us4 h0, h1;
                h0.x = th[0]; h0.y = th[1]; h0.z = th[2]; h0.w = th[3];
                h1.x = th[4]; h1.y = th[5]; h1.z = th[6]; h1.w = th[7];
                int off = n * 64 + ((k8 ^ gsw(n & 15)) * 8);
                *reinterpret_cast<us4*>(&Bh[off])     = h0;
                *reinterpret_cast<us4*>(&Bh[off + 4]) = h1;
            }
        }
        __syncthreads();

        const int row = lane & 15;
        const int kq  = lane >> 4;
        const int gr  = gsw(row);
#pragma unroll
        for (int ks = 0; ks < 2; ++ks) {
            const int k8 = ks * 4 + kq;
            bf16x8 bh[2];
#pragma unroll
            for (int ni = 0; ni < 2; ++ni) {
                int n = wn * 32 + ni * 16 + row;
                bh[ni] = *reinterpret_cast<const bf16x8*>(&Bh[n * 64 + ((k8 ^ gr) * 8)]);
            }
#pragma unroll
            for (int mi = 0; mi < 4; ++mi) {
                int m = wm * 64 + mi * 16 + row;
                bf16x8 ah = *reinterpret_cast<const bf16x8*>(&Ah[m * 64 + ((k8 ^ gr) * 8)]);
#pragma unroll
                for (int ni = 0; ni < 2; ++ni)
                    acc[mi][ni] = __builtin_amdgcn_mfma_f32_16x16x32_bf16(ah, bh[ni], acc[mi][ni], 0, 0, 0);
            }
        }
    }

    // epilogue: gm -> (b,t); n -> (p4,ug,ln); write frag-major bf16
    const int col = lane & 15;
    const int rq  = (lane >> 4) * 4;
#pragma unroll
    for (int mi = 0; mi < 4; ++mi) {
#pragma unroll
        for (int r = 0; r < 4; ++r) {
            int gm = m0 + wm * 64 + mi * 16 + rq + r;
            int b  = gm / T_STEPS;
            int t  = gm - b * T_STEPS;
#pragma unroll
            for (int ni = 0; ni < 2; ++ni) {
                int n = n0 + wn * 32 + ni * 16 + col;
                size_t addr = (((((size_t)t * 64 + (b >> 4)) * 16 + (n >> 4)) * 64)
                               + ((b & 15) >> 2) * 16 + (n & 15)) * 4 + (b & 3);
                XZF[addr] = bf16rne(acc[mi][ni][r]);
            }
        }
    }
}

// ---------------------------------------------------------------------------
// Recurrent-only scan, U=64: z = xz_t + b + h @ U. 512 threads = 8 waves
// (ug = wid&3, bh = wid>>2), 2 batch-groups/block, grid 32, 2 waves/SIMD.
// U register-resident single bf16 (32 VGPR); h single-bf16 LDS plane,
// double-buffered; xz read as ONE coalesced us4 (r=0..3) per gate-group.
// ---------------------------------------------------------------------------
template<bool LAST_ONLY>
__global__ __launch_bounds__(512, 1)
void lstm_rec64(const u16* __restrict__ XZF,   // frag-major (t,bk,16,lane,4)
                const float* __restrict__ Uw,  // (64,256)
                const float* __restrict__ bias,// (256)
                u16* __restrict__ hout,        // (B,T,64) bf16 or unused
                float* __restrict__ hlast)     // (B,64) f32 if LAST_ONLY
{
    constexpr int U = 64, NZ = 256, KTH = 2;
    constexpr int HPLANE = 16 * U;              // per batch-group plane (u16)
    constexpr size_t XSTEP = (size_t)64 * 16 * 64 * 4;   // u16 per t

    __shared__ u16 hsh[2][2][HPLANE];           // [buf][bh][...]

    const int tid  = threadIdx.x;
    const int lane = tid & 63;
    const int wid  = tid >> 6;
    const int ln   = lane & 15;
    const int lq   = lane >> 4;
    const int ug   = wid & 3;
    const int bh   = wid >> 2;
    const int unit = ug * 16 + ln;
    const int bkw  = blockIdx.x * 2 + bh;       // batch-16 group
    const int b0   = bkw * 16;

    // U weights into registers (single RNE bf16)
    bf16x8 bwu[4][KTH];
#pragma unroll
    for (int p = 0; p < 4; ++p)
#pragma unroll
        for (int kt = 0; kt < KTH; ++kt)
#pragma unroll
            for (int e = 0; e < 8; ++e) {
                int k = kt * 32 + lq * 8 + e;
                bwu[p][kt][e] = (short)bf16rne(Uw[(size_t)k * NZ + p * U + unit]);
            }
    float breg[4];
#pragma unroll
    for (int p = 0; p < 4; ++p) breg[p] = bias[p * U + unit];

    // h state: zero buf0 plane; c = 0
    u16* hw0 = &hsh[0][bh][((unit >> 3) * 16 + lq * 4) * 8 + (unit & 7)];
    u16* hw1 = &hsh[1][bh][((unit >> 3) * 16 + lq * 4) * 8 + (unit & 7)];
    float creg[4];
#pragma unroll
    for (int r = 0; r < 4; ++r) { creg[r] = 0.f; hw0[r * 8] = 0; }

    const u16* hrd[2][KTH];
#pragma unroll
    for (int b = 0; b < 2; ++b)
#pragma unroll
        for (int kt = 0; kt < KTH; ++kt)
            hrd[b][kt] = &hsh[b][bh][((kt * 4 + lq) * 16 + ln) * 8];

    // xz pointers: one us4 per p4 (coalesced: lane*4 u16)
    const u16* pxz = XZF + (((size_t)0 * 64 + bkw) * 16) * 256 + lane * 4;
    us4 xzv[4];
#pragma unroll
    for (int p = 0; p < 4; ++p)
        xzv[p] = *reinterpret_cast<const us4*>(pxz + ((size_t)p * 4 + ug) * 256);

    block_sync_lds();

#define RSTEP(CUR, OTH, tc)                                                     \
    {                                                                           \
        f32x4 acc[4] = {};                                                      \
        _Pragma("unroll")                                                       \
        for (int kt = 0; kt < KTH; ++kt) {                                      \
            bf16x8 ah = *reinterpret_cast<const bf16x8*>(hrd[CUR][kt]);         \
            _Pragma("unroll")                                                   \
            for (int p = 0; p < 4; ++p)                                         \
                acc[p] = __builtin_amdgcn_mfma_f32_16x16x32_bf16(ah, bwu[p][kt], acc[p], 0, 0, 0); \
        }                                                                       \
        us4 xcur[4];                                                            \
        _Pragma("unroll")                                                       \
        for (int p = 0; p < 4; ++p) xcur[p] = xzv[p];                           \
        if ((tc) + 1 < T_STEPS) {                                               \
            pxz += XSTEP;                                                       \
            _Pragma("unroll")                                                   \
            for (int p = 0; p < 4; ++p)                                         \
                xzv[p] = *reinterpret_cast<const us4*>(pxz + ((size_t)p * 4 + ug) * 256); \
        }                                                                       \
        _Pragma("unroll")                                                       \
        for (int r = 0; r < 4; ++r) {                                           \
            float zi = acc[0][r] + bf2f(xcur[0][r]) + breg[0];                  \
            float zf = acc[1][r] + bf2f(xcur[1][r]) + breg[1];                  \
            float zg = acc[2][r] + bf2f(xcur[2][r]) + breg[2];                  \
            float zo = acc[3][r] + bf2f(xcur[3][r]) + breg[3];                  \
            float si = fast_sigmoid(zi);                                        \
            float sf = fast_sigmoid(zf);                                        \
            float gg = fmaxf(zg, 0.f);                                          \
            float so = fast_sigmoid(zo);                                        \
            float c  = sf * creg[r] + si * gg;                                  \
            creg[r] = c;                                                        \
            float h = so * fmaxf(c, 0.f);                                       \
            u16 hb = bf16rne(h);                                                \
            ((OTH) ? hw1 : hw0)[r * 8] = hb;                                    \
            if constexpr (!LAST_ONLY) {                                         \
                hout[((size_t)(b0 + lq * 4 + r) * T_STEPS + (tc)) * U + unit] = hb; \
            } else {                                                            \
                if ((tc) == T_STEPS - 1)                                        \
                    hlast[(size_t)(b0 + lq * 4 + r) * U + unit] = h;            \
            }                                                                   \
        }                                                                       \
        block_sync_lds();                                                       \
    }

    for (int t = 0; t < T_STEPS; t += 2) {
        RSTEP(0, 1, t)
        RSTEP(1, 0, t + 1)
    }
#undef RSTEP
}

// ---------------------------------------------------------------------------
// L2 (U=128): R13's proven combined kernel (54 us). 512 threads = 8 waves.
// z = b + h1_t @ W2 (W2 in LDS, bf16) + h @ U2 (hi/lo 2-term, U2 in regs).
// Global output: hi plane only (gemm3 consumes single-term).
// ---------------------------------------------------------------------------
__global__ __launch_bounds__(512, 1)
void lstm_l2(const u16* __restrict__ xhi,    // h1 (B,T,64) bf16
             const float* __restrict__ W,    // (64,512)
             const float* __restrict__ Uw,   // (128,512)
             const float* __restrict__ bias, // (512)
             u16* __restrict__ hhi)          // (B,T,128) bf16
{
    constexpr int U = 128, NZ = 512, KTH = 4, NB = 16, KXD = 64, KTX = 2;
    constexpr int HPLANE = NB * U;
    __shared__ u16 hsh[4 * HPLANE];
    __shared__ u16 Wl[KXD * NZ];

    const int tid  = threadIdx.x;
    const int lane = tid & 63;
    const int wid  = tid >> 6;
    const int ln   = lane & 15;
    const int lq   = lane >> 4;
    const int unit = wid * 16 + ln;
    const int b0   = blockIdx.x * NB;

    for (int idx = tid; idx < KXD * NZ; idx += 512) {
        int k = idx >> 9, n = idx & (NZ - 1);
        Wl[((k >> 3) * NZ + n) * 8 + (k & 7)] = bf16rne(W[(size_t)k * NZ + n]);
    }

    bf16x8 bwu[4][KTH];
#pragma unroll
    for (int p = 0; p < 4; ++p)
#pragma unroll
        for (int kt = 0; kt < KTH; ++kt)
#pragma unroll
            for (int e = 0; e < 8; ++e) {
                int k = kt * 32 + lq * 8 + e;
                bwu[p][kt][e] = (short)bf16rne(Uw[(size_t)k * NZ + p * U + unit]);
            }
    float breg[4];
#pragma unroll
    for (int p = 0; p < 4; ++p) breg[p] = bias[p * U + unit];

    u16* hw0 = hsh + ((unit >> 3) * NB + lq * 4) * 8 + (unit & 7);
    u16* hw1 = hw0 + 2 * HPLANE;
    float creg[4];
#pragma unroll
    for (int r = 0; r < 4; ++r) {
        creg[r] = 0.f;
        hw0[r * 8] = 0;
        hw0[HPLANE + r * 8] = 0;
    }

    const u16* hrd[2][KTH];
#pragma unroll
    for (int b = 0; b < 2; ++b)
#pragma unroll
        for (int kt = 0; kt < KTH; ++kt)
            hrd[b][kt] = hsh + b * 2 * HPLANE + ((kt * 4 + lq) * NB + ln) * 8;

    const u16* wb = Wl + ((size_t)lq * NZ + unit) * 8;

    const u16* pxh = xhi + ((size_t)(b0 + ln) * T_STEPS) * KXD + lq * 8;
    bf16x8 xfh[KTX];
#pragma unroll
    for (int kt = 0; kt < KTX; ++kt)
        xfh[kt] = *reinterpret_cast<const bf16x8*>(pxh + kt * 32);

    size_t ho = ((size_t)(b0 + lq * 4) * T_STEPS) * U + unit;

    block_sync_lds();

#define L2STEP(CUR, OTH, tc)                                                    \
    {                                                                           \
        f32x4 acc[4] = {};                                                      \
        _Pragma("unroll")                                                       \
        for (int kt = 0; kt < KTH; ++kt) {                                      \
            bf16x8 ahh = *reinterpret_cast<const bf16x8*>(hrd[CUR][kt]);        \
            _Pragma("unroll")                                                   \
            for (int p = 0; p < 4; ++p)                                         \
                acc[p] = __builtin_amdgcn_mfma_f32_16x16x32_bf16(ahh, bwu[p][kt], acc[p], 0, 0, 0); \
        }                                                                       \
        _Pragma("unroll")                                                       \
        for (int kt = 0; kt < KTX; ++kt)                                        \
        _Pragma("unroll")                                                       \
        for (int p = 0; p < 4; ++p) {                                           \
            bf16x8 wf = *reinterpret_cast<const bf16x8*>(wb + ((size_t)kt * 4 * NZ + p * U) * 8); \
            acc[p] = __builtin_amdgcn_mfma_f32_16x16x32_bf16(xfh[kt], wf, acc[p], 0, 0, 0); \
        }                                                                       \
        if ((tc) + 1 < T_STEPS) {                                               \
            pxh += KXD;                                                         \
            _Pragma("unroll")                                                   \
            for (int kt = 0; kt < KTX; ++kt)                                    \
                xfh[kt] = *reinterpret_cast<const bf16x8*>(pxh + kt * 32);      \
        }                                                                       \
        _Pragma("unroll")                                                       \
        for (int r = 0; r < 4; ++r) {                                           \
            float si = fast_sigmoid(acc[0][r] + breg[0]);                       \
            float sf = fast_sigmoid(acc[1][r] + breg[1]);                       \
            float gg = fmaxf(acc[2][r] + breg[2], 0.f);                         \
            float so = fast_sigmoid(acc[3][r] + breg[3]);                       \
            float c  = sf * creg[r] + si * gg;                                  \
            creg[r] = c;                                                        \
            float h = so * fmaxf(c, 0.f);                                       \
            u16 hb = bf16rne(h);                                                \
            u16* hw = (OTH) ? hw1 : hw0;                                        \
            hw[r * 8] = hb;                                                     \
            hw[HPLANE + r * 8] = hb; /* lo plane unused downstream; keep zeroless */ \
            hhi[ho + (size_t)r * (T_STEPS * U) + (size_t)(tc) * U] = hb;        \
        }                                                                       \
        block_sync_lds();                                                       \
    }

    for (int t = 0; t < T_STEPS; t += 2) {
        L2STEP(0, 1, t)
        L2STEP(1, 0, t + 1)
    }
#undef L2STEP
}

// Dense head: one wave per batch row. 64 ->relu-> 64 ->relu-> 32 -> 101 -> softmax
__global__ __launch_bounds__(256)
void dense_head(const float* __restrict__ h3,    // (B,64)
                const float* __restrict__ Wd1, const float* __restrict__ bd1,
                const float* __restrict__ Wd2, const float* __restrict__ bd2,
                const float* __restrict__ Wd3, const float* __restrict__ bd3,
                float* __restrict__ out)         // (B,101)
{
    __shared__ float s1[4][64];
    __shared__ float s2[4][32];
    const int w    = threadIdx.x >> 6;
    const int lane = threadIdx.x & 63;
    const int row  = blockIdx.x * 4 + w;

    float hval = h3[(size_t)row * 64 + lane];
    float a = bd1[lane];
#pragma unroll
    for (int k = 0; k < 64; ++k) {
        float hk = __shfl(hval, k, 64);
        a = fmaf(hk, Wd1[k * 64 + lane], a);
    }
    s1[w][lane] = fmaxf(a, 0.f);
    __syncthreads();

    if (lane < 32) {
        float a2 = bd2[lane];
#pragma unroll
        for (int k = 0; k < 64; ++k) a2 = fmaf(s1[w][k], Wd2[k * 32 + lane], a2);
        s2[w][lane] = fmaxf(a2, 0.f);
    }
    __syncthreads();

    float a0 = bd3[lane];
#pragma unroll
    for (int k = 0; k < 32; ++k) a0 = fmaf(s2[w][k], Wd3[k * 101 + lane], a0);
    float a1 = -INFINITY;
    if (lane < 37) {
        a1 = bd3[64 + lane];
#pragma unroll
        for (int k = 0; k < 32; ++k) a1 = fmaf(s2[w][k], Wd3[k * 101 + 64 + lane], a1);
    }

    float m = fmaxf(a0, a1);
#pragma unroll
    for (int off = 32; off > 0; off >>= 1) m = fmaxf(m, __shfl_xor(m, off, 64));
    float e0 = expf(a0 - m);
    float e1 = (lane < 37) ? expf(a1 - m) : 0.f;
    float s = e0 + e1;
#pragma unroll
    for (int off = 32; off > 0; off >>= 1) s += __shfl_xor(s, off, 64);

    out[(size_t)row * 101 + lane] = e0 / s;
    if (lane < 37) out[(size_t)row * 101 + 64 + lane] = e1 / s;
}

extern "C" void kernel_launch(void* const* d_in, const int* in_sizes, int n_in,
                              void* d_out, int out_size, void* d_ws, size_t ws_size,
                              hipStream_t stream) {
    const float* x   = (const float*)d_in[0];
    const float* W1  = (const float*)d_in[1];
    const float* U1  = (const float*)d_in[2];
    const float* b1  = (const float*)d_in[3];
    const float* W2  = (const float*)d_in[4];
    const float* U2  = (const float*)d_in[5];
    const float* b2  = (const float*)d_in[6];
    const float* W3  = (const float*)d_in[7];
    const float* U3  = (const float*)d_in[8];
    const float* b3  = (const float*)d_in[9];
    const float* Wd1 = (const float*)d_in[10];
    const float* bd1 = (const float*)d_in[11];
    const float* Wd2 = (const float*)d_in[12];
    const float* bd2 = (const float*)d_in[13];
    const float* Wd3 = (const float*)d_in[14];
    const float* bd3 = (const float*)d_in[15];

    // workspace (u16 units)
    u16* ws16 = (u16*)d_ws;
    u16* xzf  = ws16;                         // frag-major xz arena: 120*64*16*64*4 = 31,457,280 (63 MB)
    u16* h1   = ws16 + 31457280;              // (B,T,64)  bf16 = 7,864,320
    u16* h2   = h1 + 7864320;                 // (B,T,128) bf16 = 15,728,640
    float* h3 = (float*)(ws16 + 55050240);    // (B,64) f32

    // 1) xz1 = x @ W1  (A fp32, K=132, N=256) -> frag-major bf16
    gemm_xz<true><<<dim3(960, 4), 256, 0, stream>>>(x, W1, xzf, 256, 132);
    // 2) rec1: scan over xz1 -> h1 (B,T,64) bf16
    lstm_rec64<false><<<32, 512, 0, stream>>>(xzf, U1, b1, h1, nullptr);
    // 3) L2 fused (proven): h1 + W2(LDS) + U2(regs) -> h2 (B,T,128) bf16
    lstm_l2<<<64, 512, 0, stream>>>(h1, W2, U2, b2, h2);
    // 4) xz3 = h2 @ W3  (A bf16, K=128, N=256) -> frag-major bf16 (reuse arena)
    gemm_xz<false><<<dim3(960, 4), 256, 0, stream>>>(h2, W3, xzf, 256, 128);
    // 5) rec3: scan over xz3 -> h3 (B,64) f32 (last step only)
    lstm_rec64<true><<<32, 512, 0, stream>>>(xzf, U3, b3, nullptr, h3);
    // 6) dense head + softmax
    dense_head<<<BATCH / 4, 256, 0, stream>>>(h3, Wd1, bd1, Wd2, bd2, Wd3, bd3,
                                              (float*)d_out);
}